// Round 3
// baseline (1403.301 us; speedup 1.0000x reference)
//
#include <hip/hip_runtime.h>

#define NP 1344      // B*V*P patches
#define LL 48        // points per patch
#define DD 512       // feature dim
#define LP 520       // padded LDS row stride (bf16 elems) for sQ/sK/sV
#define PP 72        // padded LDS row stride for probs (64 cols + 8 pad)
#define SCALE 0.04419417382415922f  // 512^-0.5
#define NEG_BIG -3.0e38f

typedef __attribute__((ext_vector_type(8))) short bf16x8;
typedef __attribute__((ext_vector_type(4))) float f32x4;

__device__ __forceinline__ short f2bf(float f) {   // fp32 -> bf16, round-nearest-even
  union { float f; unsigned int i; } x; x.f = f;
  unsigned int i = x.i;
  unsigned int r = (i + 0x7fffu + ((i >> 16) & 1u)) >> 16;
  return (short)r;
}

// load 8 consecutive fp32, convert to a bf16x8 MFMA fragment
__device__ __forceinline__ bf16x8 lda(const float* __restrict__ p) {
  float4 u = *(const float4*)p;
  float4 w = *(const float4*)(p + 4);
  bf16x8 r;
  r[0] = f2bf(u.x); r[1] = f2bf(u.y); r[2] = f2bf(u.z); r[3] = f2bf(u.w);
  r[4] = f2bf(w.x); r[5] = f2bf(w.y); r[6] = f2bf(w.z); r[7] = f2bf(w.w);
  return r;
}

// prologue: convert Wq/Wkv/Wo (fp32, 512x512 each) -> bf16 in ws
__global__ void cvt_weights(const float* __restrict__ Wq,
                            const float* __restrict__ Wkv,
                            const float* __restrict__ Wo,
                            short* __restrict__ ws) {
  const int idx = blockIdx.x * blockDim.x + threadIdx.x;  // 0..196607 float4-groups
  const float* src = (idx < 65536) ? Wq : (idx < 131072) ? Wkv : Wo;
  const int mbase  = (idx < 65536) ? 0  : (idx < 131072) ? 262144 : 524288;
  const int local  = idx & 65535;
  float4 v = ((const float4*)src)[local];
  short4 o;
  o.x = f2bf(v.x); o.y = f2bf(v.y); o.z = f2bf(v.z); o.w = f2bf(v.w);
  ((short4*)(ws + mbase))[local] = o;
}

// out[l][e] = sum_d A[l][d]*W[e][d] + b[e]; 48x512 tile, each wave owns 4 e-tiles.
// A-frag: A[m=lane&15][k=(lane>>4)*8+j]; B-frag: W[n=lane&15][k]; D: row=(lane>>4)*4+r, col=lane&15.
__device__ __forceinline__ void proj_g(const float* __restrict__ Ag,   // fp32, row stride DD
                                       const short* __restrict__ Wg,   // bf16 [512][512]
                                       const float* __restrict__ bg,   // fp32 bias
                                       short* sOut,                    // bf16, row stride LP
                                       int wave, int q4, int c16) {
  f32x4 acc[3][4];
#pragma unroll
  for (int mi = 0; mi < 3; ++mi)
#pragma unroll
    for (int ni = 0; ni < 4; ++ni)
      acc[mi][ni] = (f32x4){0.f, 0.f, 0.f, 0.f};

  for (int ks = 0; ks < 16; ++ks) {
    const int k0 = ks * 32 + q4 * 8;
    bf16x8 a[3], b[4];
#pragma unroll
    for (int mi = 0; mi < 3; ++mi)
      a[mi] = lda(Ag + (mi * 16 + c16) * DD + k0);
#pragma unroll
    for (int ni = 0; ni < 4; ++ni)
      b[ni] = *(const bf16x8*)(Wg + ((wave * 4 + ni) * 16 + c16) * DD + k0);
#pragma unroll
    for (int mi = 0; mi < 3; ++mi)
#pragma unroll
      for (int ni = 0; ni < 4; ++ni)
        acc[mi][ni] = __builtin_amdgcn_mfma_f32_16x16x32_bf16(a[mi], b[ni], acc[mi][ni], 0, 0, 0);
  }
#pragma unroll
  for (int ni = 0; ni < 4; ++ni) {
    const int e = (wave * 4 + ni) * 16 + c16;
    const float bias = bg[e];
#pragma unroll
    for (int mi = 0; mi < 3; ++mi)
#pragma unroll
      for (int r = 0; r < 4; ++r)
        sOut[(mi * 16 + q4 * 4 + r) * LP + e] = f2bf(acc[mi][ni][r] + bias);
  }
}

__global__ __launch_bounds__(512, 1)
void attn_pointlevel_fused(const float* __restrict__ Xq,
                           const float* __restrict__ Xk,
                           const float* __restrict__ Xv,
                           const short* __restrict__ Wq,   // bf16 (pre-converted)
                           const float* __restrict__ bq,
                           const short* __restrict__ Wkv,  // bf16
                           const float* __restrict__ bkv,
                           const short* __restrict__ Wo,   // bf16
                           const float* __restrict__ bo,
                           float* __restrict__ out) {
  // LDS: 3*48*520*2 + 48*72*2 = 156672 B  (<=160 KiB -> 1 block/CU)
  __shared__ __align__(16) short sQ[LL * LP];
  __shared__ __align__(16) short sK[LL * LP];
  __shared__ __align__(16) short sV[LL * LP];
  __shared__ __align__(16) short sP[LL * PP];

  const int tid  = threadIdx.x;
  const int wave = tid >> 6;     // 0..7
  const int lane = tid & 63;
  const int q4   = lane >> 4;    // 0..3
  const int c16  = lane & 15;    // 0..15
  const int patch = blockIdx.x;
  const int base  = patch * (LL * DD);

  // ---- phase 1: Q and K projections (all 8 waves) ----
  proj_g(Xq + base, Wq, bq, sQ, wave, q4, c16);
  proj_g(Xk + base, Wkv, bkv, sK, wave, q4, c16);
  __syncthreads();

  // ---- phase 2 (split): waves 0-2 scores+softmax -> sP;  waves 3-7 V-proj -> sV ----
  if (wave < 3) {
    const int ti = wave;         // row-block this wave owns
    f32x4 sc[3];
#pragma unroll
    for (int tj = 0; tj < 3; ++tj) sc[tj] = (f32x4){0.f, 0.f, 0.f, 0.f};

    for (int ks = 0; ks < 16; ++ks) {
      const int k0 = ks * 32 + q4 * 8;
      bf16x8 aq = *(const bf16x8*)(sQ + (ti * 16 + c16) * LP + k0);
#pragma unroll
      for (int tj = 0; tj < 3; ++tj) {
        bf16x8 bk = *(const bf16x8*)(sK + (tj * 16 + c16) * LP + k0);
        sc[tj] = __builtin_amdgcn_mfma_f32_16x16x32_bf16(aq, bk, sc[tj], 0, 0, 0);
      }
    }
    // softmax: row l = ti*16 + q4*4 + r lives in the 16 lanes of this quad (c16=0..15),
    // 3 cols per lane (tj*16 + c16). Reduce with shfl_xor width 16.
#pragma unroll
    for (int r = 0; r < 4; ++r) {
      const int l = ti * 16 + q4 * 4 + r;
      float v0 = sc[0][r], v1 = sc[1][r], v2 = sc[2][r];
      const bool m0 = (c16 == l), m1 = (16 + c16 == l), m2 = (32 + c16 == l);
      float mx = fmaxf(fmaxf(m0 ? NEG_BIG : v0, m1 ? NEG_BIG : v1), m2 ? NEG_BIG : v2);
#pragma unroll
      for (int s = 1; s < 16; s <<= 1) mx = fmaxf(mx, __shfl_xor(mx, s, 16));
      float e0 = m0 ? 0.f : __expf((v0 - mx) * SCALE);
      float e1 = m1 ? 0.f : __expf((v1 - mx) * SCALE);
      float e2 = m2 ? 0.f : __expf((v2 - mx) * SCALE);
      float sum = e0 + e1 + e2;
#pragma unroll
      for (int s = 1; s < 16; s <<= 1) sum += __shfl_xor(sum, s, 16);
      const float inv = 1.0f / sum;
      sP[l * PP + c16]      = f2bf(e0 * inv);
      sP[l * PP + 16 + c16] = f2bf(e1 * inv);
      sP[l * PP + 32 + c16] = f2bf(e2 * inv);
      sP[l * PP + 48 + c16] = 0;   // zero-pad cols 48..63 (exact: P[:,m>=48]==0)
    }
  } else {
    // V projection: waves 3..7 split the 32 e-tiles
    const int u = wave - 3;      // 0..4
    for (int et = u; et < 32; et += 5) {
      f32x4 acc[3];
#pragma unroll
      for (int mi = 0; mi < 3; ++mi) acc[mi] = (f32x4){0.f, 0.f, 0.f, 0.f};
      for (int ks = 0; ks < 16; ++ks) {
        const int k0 = ks * 32 + q4 * 8;
        bf16x8 b = *(const bf16x8*)(Wkv + (et * 16 + c16) * DD + k0);
#pragma unroll
        for (int mi = 0; mi < 3; ++mi) {
          bf16x8 a = lda(Xv + base + (mi * 16 + c16) * DD + k0);
          acc[mi] = __builtin_amdgcn_mfma_f32_16x16x32_bf16(a, b, acc[mi], 0, 0, 0);
        }
      }
      const int e = et * 16 + c16;
      const float bias = bkv[e];
#pragma unroll
      for (int mi = 0; mi < 3; ++mi)
#pragma unroll
        for (int r = 0; r < 4; ++r)
          sV[(mi * 16 + q4 * 4 + r) * LP + e] = f2bf(acc[mi][r] + bias);
    }
  }
  __syncthreads();

  // ---- phase 3: O[l][d] = sum_m P[l][m] V[m][d]  -> back into sQ (bf16) ----
  {
    f32x4 acc[3][4];
#pragma unroll
    for (int mi = 0; mi < 3; ++mi)
#pragma unroll
      for (int ni = 0; ni < 4; ++ni)
        acc[mi][ni] = (f32x4){0.f, 0.f, 0.f, 0.f};

    for (int ks = 0; ks < 2; ++ks) {
      const int k0 = ks * 32 + q4 * 8;
      bf16x8 a[3];
#pragma unroll
      for (int mi = 0; mi < 3; ++mi)
        a[mi] = *(const bf16x8*)(sP + (mi * 16 + c16) * PP + k0);
#pragma unroll
      for (int ni = 0; ni < 4; ++ni) {
        const int dcol = (wave * 4 + ni) * 16 + c16;
        bf16x8 b;
#pragma unroll
        for (int j = 0; j < 8; ++j) {
          const int m = k0 + j;
          b[j] = (m < LL) ? sV[m * LP + dcol] : (short)0;  // rows >=48 don't exist; P==0 there
        }
#pragma unroll
        for (int mi = 0; mi < 3; ++mi)
          acc[mi][ni] = __builtin_amdgcn_mfma_f32_16x16x32_bf16(a[mi], b, acc[mi][ni], 0, 0, 0);
      }
    }
    __syncthreads();   // all phase-2/3 reads of sQ done; safe to overwrite
#pragma unroll
    for (int ni = 0; ni < 4; ++ni)
#pragma unroll
      for (int mi = 0; mi < 3; ++mi)
#pragma unroll
        for (int r = 0; r < 4; ++r)
          sQ[(mi * 16 + q4 * 4 + r) * LP + (wave * 4 + ni) * 16 + c16] =
              f2bf(acc[mi][ni][r]);
  }
  __syncthreads();

  // ---- phase 4: out = O @ Wo^T + bo  (fp32 store) ----
  {
    f32x4 acc[3][4];
#pragma unroll
    for (int mi = 0; mi < 3; ++mi)
#pragma unroll
      for (int ni = 0; ni < 4; ++ni)
        acc[mi][ni] = (f32x4){0.f, 0.f, 0.f, 0.f};

    for (int ks = 0; ks < 16; ++ks) {
      const int k0 = ks * 32 + q4 * 8;
      bf16x8 a[3], b[4];
#pragma unroll
      for (int mi = 0; mi < 3; ++mi)
        a[mi] = *(const bf16x8*)(sQ + (mi * 16 + c16) * LP + k0);
#pragma unroll
      for (int ni = 0; ni < 4; ++ni)
        b[ni] = *(const bf16x8*)(Wo + ((wave * 4 + ni) * 16 + c16) * DD + k0);
#pragma unroll
      for (int mi = 0; mi < 3; ++mi)
#pragma unroll
        for (int ni = 0; ni < 4; ++ni)
          acc[mi][ni] = __builtin_amdgcn_mfma_f32_16x16x32_bf16(a[mi], b[ni], acc[mi][ni], 0, 0, 0);
    }
#pragma unroll
    for (int ni = 0; ni < 4; ++ni) {
      const int e = (wave * 4 + ni) * 16 + c16;
      const float bias = bo[e];
#pragma unroll
      for (int mi = 0; mi < 3; ++mi)
#pragma unroll
        for (int r = 0; r < 4; ++r) {
          const int row = patch * LL + mi * 16 + q4 * 4 + r;
          out[row * DD + e] = acc[mi][ni][r] + bias;
        }
    }
  }
}

extern "C" void kernel_launch(void* const* d_in, const int* in_sizes, int n_in,
                              void* d_out, int out_size, void* d_ws, size_t ws_size,
                              hipStream_t stream) {
  const float* Xq  = (const float*)d_in[0];  // queries  fp32
  const float* Xk  = (const float*)d_in[1];  // keys     fp32
  const float* Xv  = (const float*)d_in[2];  // values   fp32
  const float* Wq  = (const float*)d_in[3];
  const float* bq  = (const float*)d_in[4];
  const float* Wkv = (const float*)d_in[5];
  const float* bkv = (const float*)d_in[6];
  const float* Wo  = (const float*)d_in[7];
  const float* bo  = (const float*)d_in[8];
  float* outp = (float*)d_out;

  short* wsW = (short*)d_ws;                 // 3 * 512*512 bf16 = 1.57 MB

  cvt_weights<<<dim3(768), dim3(256), 0, stream>>>(Wq, Wkv, Wo, wsW);
  attn_pointlevel_fused<<<dim3(NP), dim3(512), 0, stream>>>(
      Xq, Xk, Xv,
      wsW, bq, wsW + 262144, bkv, wsW + 524288, bo,
      outp);
}